// Round 13
// baseline (1016.259 us; speedup 1.0000x reference)
//
#include <hip/hip_runtime.h>
#include <math.h>

#define NCLS 9

typedef __attribute__((ext_vector_type(8))) short short8;
typedef __attribute__((ext_vector_type(4))) float f32x4;

__device__ __forceinline__ unsigned short f2bf(float f) {
    unsigned int u = __float_as_uint(f);
    return (unsigned short)((u + 0x7fffu + ((u >> 16) & 1u)) >> 16);  // RNE
}

__device__ __forceinline__ short8 as_s8(uint4 v) {
    union { uint4 u; short8 s; } x; x.u = v; return x.s;
}

__device__ __forceinline__ float fast_tanh(float x) {
    // tanh(x) = 1 - 2/(2^(x*2*log2e) + 1); saturates correctly at +/-1
    float s = x * 2.885390081777927f;
    float e, r;
    asm("v_exp_f32 %0, %1" : "=v"(e) : "v"(s));
    asm("v_rcp_f32 %0, %1" : "=v"(r) : "v"(e + 1.0f));
    return fmaf(-2.0f, r, 1.0f);
}

// Fused 2-layer persistent MFMA RNN. M=1 row/block, C=64 cols/wave, 4 waves,
// grid 512 -> TWO INDEPENDENT BLOCKS PER CU. Same DS traffic per CU as R11
// (64 ds_read_b128 / 2 rows), but the two blocks have independent barrier
// domains: one block's MFMA/DS issue hides under the other's barrier wait and
// trans tail (the ~400cyc residual R6-R12 could not remove).
//
// U residency at C=64 (4 tiles x 8 kk = 128 regs) via the R9-proven AGPR pin:
// "+a" asm once per layer. VGPR ~100 + AGPR 128 = 228 <= 256 ->
// __launch_bounds__(256,2) allows 2 waves/SIMD (2 blocks/CU co-resident).
//
// h LDS (M=1): 32 cells x 16B per buffer; cell (kk,g2) = idx kk*4+g2 holds
// k = kk*32+g2*8+0..7 of the single row.
//  - A-read (per kk): lane (g,l16) reads cell (kk,g): 4 distinct cells,
//    16-fold same-address broadcast, 16 distinct banks -> conflict-free.
//  - h-write (g==0): b32 per col-pair, 16 distinct banks -> conflict-free.
// Row-duplication: all 16 A-rows = row 0 -> C rows identical; keep r=0 only.
__global__ __launch_bounds__(256, 2) void rnn_fused_kernel(
    const float* __restrict__ x,     // [B, 1024]
    const float* __restrict__ W1, const float* __restrict__ U1, const float* __restrict__ b1,
    const float* __restrict__ W2, const float* __restrict__ U2, const float* __restrict__ b2,
    float* __restrict__ h2out)       // [B, 256]
{
    const int tid  = threadIdx.x;
    const int w    = tid >> 6;    // wave 0..3: cols [w*64, w*64+64)
    const int lane = tid & 63;
    const int g    = lane >> 4;
    const int l16  = lane & 15;
    const int b0   = blockIdx.x;  // ONE batch row per block

    __shared__ uint4 hbuf[2][32];    // 2 x 512B h double-buffer (cell layout)
    __shared__ float xall[1025];     // 4KB+pad: x staged [t] (padded prefetch)
    __shared__ float seq2[257];      // 1KB+pad: layer-2 input [col]

    // ---- stage all of x (once) + zero both h buffers ----
    {
        const float4* x4 = (const float4*)x;
        const float4 v = x4[b0 * 256 + tid];
        *(float4*)&xall[tid * 4] = v;
        ((unsigned int*)hbuf)[tid] = 0u;     // 256 u32 = both buffers
        if (tid == 0) xall[1024] = 0.0f;     // pad (read, never consumed)
    }

    // ---- hoisted LDS byte offsets ----
    int rd_off[8];
    #pragma unroll
    for (int kk = 0; kk < 8; ++kk)
        rd_off[kk] = (kk * 4 + g) << 4;
    int wr_off[2];
    #pragma unroll
    for (int u = 0; u < 2; ++u)
        wr_off[u] = (((w * 2 + u) * 4 + (l16 >> 2)) << 4) + ((l16 & 3) << 2);
    char* const hbase = (char*)hbuf;

#pragma unroll 1
    for (int p = 0; p < 2; ++p) {
        const float* W    = p ? W2 : W1;
        const float* U    = p ? U2 : U1;
        const float* bias = p ? b2 : b1;
        const int    T    = p ? 256 : 1024;

        // ---- B-fragments: tile (u,v): col = w*64 + u*32 + 2c + v ----
        uint4 bfrag[2][2][8];
        #pragma unroll
        for (int u = 0; u < 2; ++u) {
            #pragma unroll
            for (int v = 0; v < 2; ++v) {
                const int col = w * 64 + u * 32 + 2 * l16 + v;
                #pragma unroll
                for (int kk = 0; kk < 8; ++kk) {
                    unsigned int d[4];
                    #pragma unroll
                    for (int pr = 0; pr < 4; ++pr) {
                        const int k0 = kk * 32 + g * 8 + 2 * pr;
                        d[pr] = (unsigned)f2bf(U[k0 * 256 + col])
                              | ((unsigned)f2bf(U[(k0 + 1) * 256 + col]) << 16);
                    }
                    bfrag[u][v][kk] = make_uint4(d[0], d[1], d[2], d[3]);
                }
            }
        }
        // ---- ONE-TIME AGPR pin (R9-proven residency mechanism) ----
        #pragma unroll
        for (int u = 0; u < 2; ++u)
            #pragma unroll
            for (int v = 0; v < 2; ++v)
                #pragma unroll
                for (int kk = 0; kk < 8; ++kk)
                    asm volatile("" : "+a"(bfrag[u][v][kk].x), "+a"(bfrag[u][v][kk].y),
                                      "+a"(bfrag[u][v][kk].z), "+a"(bfrag[u][v][kk].w));

        // W/bias: float2 per tile-pair u -> (col, col+1)
        const float2 wv[2] = { *(const float2*)&W[w * 64 + 2 * l16],
                               *(const float2*)&W[w * 64 + 32 + 2 * l16] };
        const float2 bv[2] = { *(const float2*)&bias[w * 64 + 2 * l16],
                               *(const float2*)&bias[w * 64 + 32 + 2 * l16] };

        if (p == 1) {
            // re-zero h buffer 0 for layer 2 (first 512B = 128 u32)
            if (tid < 128) ((unsigned int*)hbuf)[tid] = 0u;
        }
        __syncthreads();

        const float* const svp = p ? seq2 : xall;
        float svc = svp[0];

        for (int t = 0; t < T; ++t) {
            char* const hcur = hbase + ((t & 1) << 9);
            char* const hnxt = hbase + (((t & 1) ^ 1) << 9);

            // A-fragments: 8 x ds_read_b128, 4 cells each, x16 broadcast
            uint4 a[8];
            #pragma unroll
            for (int kk = 0; kk < 8; ++kk)
                a[kk] = *(const uint4*)(hcur + rd_off[kk]);

            // acc init = input projection + bias (all C rows identical)
            f32x4 accE[2][2], accO[2][2];
            #pragma unroll
            for (int u = 0; u < 2; ++u) {
                const float i0 = fmaf(svc, wv[u].x, bv[u].x);
                const float i1 = fmaf(svc, wv[u].y, bv[u].y);
                accE[u][0] = (f32x4){i0, i0, i0, i0};
                accE[u][1] = (f32x4){i1, i1, i1, i1};
                accO[u][0] = (f32x4){0.f, 0.f, 0.f, 0.f};
                accO[u][1] = (f32x4){0.f, 0.f, 0.f, 0.f};
            }

            // 8 independent 4-deep MFMA chains (4 tiles x even/odd kk)
            #pragma unroll
            for (int kp = 0; kp < 4; ++kp) {
                #pragma unroll
                for (int u = 0; u < 2; ++u)
                    #pragma unroll
                    for (int v = 0; v < 2; ++v) {
                        accE[u][v] = __builtin_amdgcn_mfma_f32_16x16x32_bf16(
                            as_s8(a[2 * kp]), as_s8(bfrag[u][v][2 * kp]), accE[u][v], 0, 0, 0);
                        accO[u][v] = __builtin_amdgcn_mfma_f32_16x16x32_bf16(
                            as_s8(a[2 * kp + 1]), as_s8(bfrag[u][v][2 * kp + 1]), accO[u][v], 0, 0, 0);
                    }
            }

            // prefetch sv for t+1 (padded arrays: no select)
            svc = svp[t + 1];

            // epilogue: row 0 only; 4 tanh, 2 cvt_pk, 2 b32 writes (g==0)
            const float h00 = fast_tanh(accE[0][0][0] + accO[0][0][0]);
            const float h01 = fast_tanh(accE[0][1][0] + accO[0][1][0]);
            const float h10 = fast_tanh(accE[1][0][0] + accO[1][0][0]);
            const float h11 = fast_tanh(accE[1][1][0] + accO[1][1][0]);
            unsigned pk0, pk1;
            asm("v_cvt_pk_bf16_f32 %0, %1, %2" : "=v"(pk0) : "v"(h00), "v"(h01));
            asm("v_cvt_pk_bf16_f32 %0, %1, %2" : "=v"(pk1) : "v"(h10), "v"(h11));

            if (g == 0) {
                *(unsigned int*)(hnxt + wr_off[0]) = pk0;
                *(unsigned int*)(hnxt + wr_off[1]) = pk1;
                if (t == T - 1) {
                    if (p == 0) {
                        *(float2*)&seq2[w * 64 + 2 * l16]      = make_float2(h00, h01);
                        *(float2*)&seq2[w * 64 + 32 + 2 * l16] = make_float2(h10, h11);
                    } else {
                        *(float2*)&h2out[b0 * 256 + w * 64 + 2 * l16]      = make_float2(h00, h01);
                        *(float2*)&h2out[b0 * 256 + w * 64 + 32 + 2 * l16] = make_float2(h10, h11);
                    }
                }
            }
            __syncthreads();
        }
    }
}

// Tiny MLP head: one block per batch row, 128 threads.
__global__ __launch_bounds__(128) void mlp_kernel(
    const float* __restrict__ h2,
    const float* __restrict__ Wd1, const float* __restrict__ bd1,
    const float* __restrict__ Wd2, const float* __restrict__ bd2,
    const float* __restrict__ Wd3, const float* __restrict__ bd3,
    const float* __restrict__ Wd4, const float* __restrict__ bd4,
    float* __restrict__ out)
{
    const int b   = blockIdx.x;
    const int tid = threadIdx.x;

    __shared__ float hin[256];
    __shared__ float z1[128];
    __shared__ float z2[64];
    __shared__ float z3[32];

    hin[tid]       = h2[b * 256 + tid];
    hin[tid + 128] = h2[b * 256 + tid + 128];
    __syncthreads();

    {
        float a = bd1[tid];
#pragma unroll 8
        for (int i = 0; i < 256; ++i) a += hin[i] * Wd1[i * 128 + tid];
        z1[tid] = fmaxf(a, 0.0f);
    }
    __syncthreads();
    if (tid < 64) {
        float a = bd2[tid];
#pragma unroll 8
        for (int i = 0; i < 128; ++i) a += z1[i] * Wd2[i * 64 + tid];
        z2[tid] = fmaxf(a, 0.0f);
    }
    __syncthreads();
    if (tid < 32) {
        float a = bd3[tid];
#pragma unroll 8
        for (int i = 0; i < 64; ++i) a += z2[i] * Wd3[i * 32 + tid];
        z3[tid] = fmaxf(a, 0.0f);
    }
    __syncthreads();
    if (tid < NCLS) {
        float a = bd4[tid];
#pragma unroll
        for (int i = 0; i < 32; ++i) a += z3[i] * Wd4[i * NCLS + tid];
        out[b * NCLS + tid] = a;
    }
}

extern "C" void kernel_launch(void* const* d_in, const int* in_sizes, int n_in,
                              void* d_out, int out_size, void* d_ws, size_t ws_size,
                              hipStream_t stream) {
    const float* x   = (const float*)d_in[0];
    const float* W1  = (const float*)d_in[1];
    const float* U1  = (const float*)d_in[2];
    const float* b1  = (const float*)d_in[3];
    const float* W2  = (const float*)d_in[4];
    const float* U2  = (const float*)d_in[5];
    const float* b2  = (const float*)d_in[6];
    const float* Wd1 = (const float*)d_in[7];
    const float* bd1 = (const float*)d_in[8];
    const float* Wd2 = (const float*)d_in[9];
    const float* bd2 = (const float*)d_in[10];
    const float* Wd3 = (const float*)d_in[11];
    const float* bd3 = (const float*)d_in[12];
    const float* Wd4 = (const float*)d_in[13];
    const float* bd4 = (const float*)d_in[14];

    float* out = (float*)d_out;
    float* h2  = (float*)d_ws;        // 512*256 fp32

    rnn_fused_kernel<<<512, 256, 0, stream>>>(x, W1, U1, b1, W2, U2, b2, h2);
    mlp_kernel<<<512, 128, 0, stream>>>(h2, Wd1, bd1, Wd2, bd2, Wd3, bd3, Wd4, bd4, out);
}

// Round 14
// 641.038 us; speedup vs baseline: 1.5853x; 1.5853x over previous
//
#include <hip/hip_runtime.h>
#include <math.h>

#define NCLS 9

typedef __attribute__((ext_vector_type(8))) short short8;
typedef __attribute__((ext_vector_type(4))) float f32x4;

__device__ __forceinline__ unsigned short f2bf(float f) {
    unsigned int u = __float_as_uint(f);
    return (unsigned short)((u + 0x7fffu + ((u >> 16) & 1u)) >> 16);  // RNE
}

__device__ __forceinline__ short8 as_s8(uint4 v) {
    union { uint4 u; short8 s; } x; x.u = v; return x.s;
}

__device__ __forceinline__ float fast_tanh(float x) {
    // tanh(x) = 1 - 2/(2^(x*2*log2e) + 1); saturates correctly at +/-1
    float s = x * 2.885390081777927f;
    float e, r;
    asm("v_exp_f32 %0, %1" : "=v"(e) : "v"(s));
    asm("v_rcp_f32 %0, %1" : "=v"(r) : "v"(e + 1.0f));
    return fmaf(-2.0f, r, 1.0f);
}

// Fused 2-layer persistent MFMA RNN + MLP head, one kernel.
// M=2 rows/block, 256 blocks (1/CU), 512 threads (8 waves, 2/SIMD).
// Wave w owns 32 output cols (2 B-tiles, 64 pinned VGPR -- the
// allocator-stable count proven in R6/R8/R11; C=64 variants all failed on
// the register wall across R3/4/7/9/13). Paired-column map
// col = w*32 + 2c + t2 -> per-row pair packs via one v_cvt_pk_bf16_f32.
//
// ROW-DUPLICATION: lane (g,l16) reads A row (l16&1); 8 lanes share each
// address (same-address broadcast = free); C rows 2..15 are consistent
// duplicates; only rows 0..1 kept.
//
// h LDS: 64 cells x 16B per buffer; cell (kk,g2,m) = idx kk*8+g2*2+m holds
// k = kk*32+g2*8+0..7 of row m.
//  - A-read (per kk): 8 distinct contiguous cells, 1 word/bank, bcast x8.
//  - h-write (g==0): b32, 16 distinct banks, conflict-free.
// DS datapath 64 x ds_read_b128 / CU-step is the structural floor at C=32.
//
// MLP head fused in the kernel tail: h2 stays in LDS (hout), Wd* are
// L2/L3-hot across blocks; writes the 2x9 logits directly. Saves the second
// launch and the 1MB h2 HBM round-trip.
__global__ __launch_bounds__(512, 2) void rnn_fused_kernel(
    const float* __restrict__ x,     // [B, 1024]
    const float* __restrict__ W1, const float* __restrict__ U1, const float* __restrict__ b1,
    const float* __restrict__ W2, const float* __restrict__ U2, const float* __restrict__ b2,
    const float* __restrict__ Wd1, const float* __restrict__ bd1,
    const float* __restrict__ Wd2, const float* __restrict__ bd2,
    const float* __restrict__ Wd3, const float* __restrict__ bd3,
    const float* __restrict__ Wd4, const float* __restrict__ bd4,
    float* __restrict__ out)         // [B, 9]
{
    const int tid  = threadIdx.x;
    const int w    = tid >> 6;
    const int lane = tid & 63;
    const int g    = lane >> 4;
    const int l16  = lane & 15;
    const int b0   = blockIdx.x << 1;   // 2 rows per block

    __shared__ uint4  hbuf[2][64];    // 2 x 1KB h double-buffer (cell layout)
    __shared__ float2 xall[1025];     // 8KB+pad: x staged [t]{row0,row1}
    __shared__ float2 seq2[257];      // 2KB+pad: layer-2 input [col]{row0,row1}
    __shared__ float  hout[2][256];   // final h2 per row
    __shared__ float  z1[2][128];
    __shared__ float  z2[2][64];
    __shared__ float  z3[2][32];

    // ---- stage all of x (once) + zero both h buffers ----
    {
        const float4* x4 = (const float4*)x;
        const int row = tid >> 8, tq = tid & 255;      // 512 threads = 2x256
        const float4 v = x4[(b0 + row) * 256 + tq];
        ((float*)&xall[tq * 4 + 0])[row] = v.x;
        ((float*)&xall[tq * 4 + 1])[row] = v.y;
        ((float*)&xall[tq * 4 + 2])[row] = v.z;
        ((float*)&xall[tq * 4 + 3])[row] = v.w;
        ((unsigned int*)hbuf)[tid] = 0u;               // 512 u32 = both buffers
        if (tid == 0) xall[1024] = make_float2(0.f, 0.f);   // prefetch pad
    }

    // ---- hoisted LDS byte offsets ----
    int rd_off[8];
    #pragma unroll
    for (int kk = 0; kk < 8; ++kk)
        rd_off[kk] = (kk * 8 + g * 2 + (l16 & 1)) << 4;
    const int g2w = (l16 >> 2) & 3, s4 = l16 & 3;
    int wr_off[2];
    #pragma unroll
    for (int r = 0; r < 2; ++r)
        wr_off[r] = ((w * 8 + g2w * 2 + r) << 4) + 4 * s4;
    const int col0 = w * 32 + 2 * l16;
    char* const hbase = (char*)hbuf;

#pragma unroll 1
    for (int p = 0; p < 2; ++p) {
        const float* W    = p ? W2 : W1;
        const float* U    = p ? U2 : U1;
        const float* bias = p ? b2 : b1;
        const int    T    = p ? 256 : 1024;

        // ---- B-fragments (bf16, pinned registers); col = w*32 + 2c + t2 ----
        uint4 bfrag[2][8];
        #pragma unroll
        for (int t2 = 0; t2 < 2; ++t2) {
            #pragma unroll
            for (int kk = 0; kk < 8; ++kk) {
                unsigned int d[4];
                #pragma unroll
                for (int pr = 0; pr < 4; ++pr) {
                    const int k0 = kk * 32 + g * 8 + 2 * pr;
                    d[pr] = (unsigned)f2bf(U[k0 * 256 + col0 + t2])
                          | ((unsigned)f2bf(U[(k0 + 1) * 256 + col0 + t2]) << 16);
                }
                bfrag[t2][kk] = make_uint4(d[0], d[1], d[2], d[3]);
            }
        }
        #pragma unroll
        for (int t2 = 0; t2 < 2; ++t2)
            #pragma unroll
            for (int kk = 0; kk < 8; ++kk)
                asm volatile("" : "+v"(bfrag[t2][kk].x), "+v"(bfrag[t2][kk].y),
                                  "+v"(bfrag[t2][kk].z), "+v"(bfrag[t2][kk].w));

        const float2 wv2 = *(const float2*)&W[col0];
        const float2 bv2 = *(const float2*)&bias[col0];

        if (p == 1) {
            // re-zero h buffer 0 for layer 2 (first 1KB = 256 u32)
            if (tid < 256) ((unsigned int*)hbuf)[tid] = 0u;
            if (tid == 0) seq2[256] = make_float2(0.f, 0.f);   // prefetch pad
        }
        __syncthreads();

        const float2* const svp = p ? seq2 : xall;
        float2 svc = svp[0];

        for (int t = 0; t < T; ++t) {
            char* const hcur = hbase + ((t & 1) << 10);
            char* const hnxt = hbase + (((t & 1) ^ 1) << 10);

            // A-fragments: 8 x ds_read_b128, 8 distinct cells, x8 broadcast
            uint4 a[8];
            #pragma unroll
            for (int kk = 0; kk < 8; ++kk)
                a[kk] = *(const uint4*)(hcur + rd_off[kk]);

            // acc init = input projection + bias; rows 2..15 mirror 0..1
            f32x4 aA0, aA1;
            f32x4 aB0 = {0.f, 0.f, 0.f, 0.f}, aB1 = {0.f, 0.f, 0.f, 0.f};
            aA0[0] = fmaf(svc.x, wv2.x, bv2.x);
            aA0[1] = fmaf(svc.y, wv2.x, bv2.x);
            aA0[2] = aA0[0]; aA0[3] = aA0[1];
            aA1[0] = fmaf(svc.x, wv2.y, bv2.y);
            aA1[1] = fmaf(svc.y, wv2.y, bv2.y);
            aA1[2] = aA1[0]; aA1[3] = aA1[1];

            // 4 independent 4-deep MFMA chains (2 tiles x even/odd kk)
            #pragma unroll
            for (int kp = 0; kp < 4; ++kp) {
                aA0 = __builtin_amdgcn_mfma_f32_16x16x32_bf16(
                    as_s8(a[2 * kp]), as_s8(bfrag[0][2 * kp]), aA0, 0, 0, 0);
                aA1 = __builtin_amdgcn_mfma_f32_16x16x32_bf16(
                    as_s8(a[2 * kp]), as_s8(bfrag[1][2 * kp]), aA1, 0, 0, 0);
                aB0 = __builtin_amdgcn_mfma_f32_16x16x32_bf16(
                    as_s8(a[2 * kp + 1]), as_s8(bfrag[0][2 * kp + 1]), aB0, 0, 0, 0);
                aB1 = __builtin_amdgcn_mfma_f32_16x16x32_bf16(
                    as_s8(a[2 * kp + 1]), as_s8(bfrag[1][2 * kp + 1]), aB1, 0, 0, 0);
            }

            // prefetch sv for t+1 (padded arrays: no select)
            svc = svp[t + 1];

            // epilogue: only rows 0,1 are real
            const float h00 = fast_tanh(aA0[0] + aB0[0]);   // col0,   row0
            const float h01 = fast_tanh(aA0[1] + aB0[1]);   // col0,   row1
            const float h10 = fast_tanh(aA1[0] + aB1[0]);   // col0+1, row0
            const float h11 = fast_tanh(aA1[1] + aB1[1]);   // col0+1, row1
            unsigned pk0, pk1;
            asm("v_cvt_pk_bf16_f32 %0, %1, %2" : "=v"(pk0) : "v"(h00), "v"(h10));
            asm("v_cvt_pk_bf16_f32 %0, %1, %2" : "=v"(pk1) : "v"(h01), "v"(h11));

            if (g == 0) {
                *(unsigned int*)(hnxt + wr_off[0]) = pk0;   // row 0
                *(unsigned int*)(hnxt + wr_off[1]) = pk1;   // row 1
                if (t == T - 1) {
                    if (p == 0) {
                        seq2[col0]     = make_float2(h00, h01);
                        seq2[col0 + 1] = make_float2(h10, h11);
                    } else {
                        hout[0][col0]     = h00;
                        hout[1][col0]     = h01;
                        hout[0][col0 + 1] = h10;
                        hout[1][col0 + 1] = h11;
                    }
                }
            }
            __syncthreads();
        }
    }

    // ---- fused MLP head: 256->128(relu)->64(relu)->32(relu)->9 ----
    // hout is visible (loop ended with __syncthreads).
    if (tid < 256) {
        const int row = tid >> 7, col = tid & 127;
        float a = bd1[col];
        #pragma unroll 8
        for (int i = 0; i < 256; ++i) a += hout[row][i] * Wd1[i * 128 + col];
        z1[row][col] = fmaxf(a, 0.0f);
    }
    __syncthreads();
    if (tid < 128) {
        const int row = tid >> 6, col = tid & 63;
        float a = bd2[col];
        #pragma unroll 8
        for (int i = 0; i < 128; ++i) a += z1[row][i] * Wd2[i * 64 + col];
        z2[row][col] = fmaxf(a, 0.0f);
    }
    __syncthreads();
    if (tid < 64) {
        const int row = tid >> 5, col = tid & 31;
        float a = bd3[col];
        #pragma unroll 8
        for (int i = 0; i < 64; ++i) a += z2[row][i] * Wd3[i * 32 + col];
        z3[row][col] = fmaxf(a, 0.0f);
    }
    __syncthreads();
    if (tid < 2 * NCLS) {
        const int row = tid / NCLS, col = tid % NCLS;
        float a = bd4[col];
        #pragma unroll
        for (int i = 0; i < 32; ++i) a += z3[row][i] * Wd4[i * NCLS + col];
        out[(b0 + row) * NCLS + col] = a;
    }
}

extern "C" void kernel_launch(void* const* d_in, const int* in_sizes, int n_in,
                              void* d_out, int out_size, void* d_ws, size_t ws_size,
                              hipStream_t stream) {
    const float* x   = (const float*)d_in[0];
    const float* W1  = (const float*)d_in[1];
    const float* U1  = (const float*)d_in[2];
    const float* b1  = (const float*)d_in[3];
    const float* W2  = (const float*)d_in[4];
    const float* U2  = (const float*)d_in[5];
    const float* b2  = (const float*)d_in[6];
    const float* Wd1 = (const float*)d_in[7];
    const float* bd1 = (const float*)d_in[8];
    const float* Wd2 = (const float*)d_in[9];
    const float* bd2 = (const float*)d_in[10];
    const float* Wd3 = (const float*)d_in[11];
    const float* bd3 = (const float*)d_in[12];
    const float* Wd4 = (const float*)d_in[13];
    const float* bd4 = (const float*)d_in[14];

    float* out = (float*)d_out;   // [512, 9]

    rnn_fused_kernel<<<256, 512, 0, stream>>>(
        x, W1, U1, b1, W2, U2, b2,
        Wd1, bd1, Wd2, bd2, Wd3, bd3, Wd4, bd4, out);
}